// Round 4
// baseline (641.922 us; speedup 1.0000x reference)
//
#include <hip/hip_runtime.h>

#define N_ 32
#define C_ 512
#define T_ 2048
#define K_ 1024
#define NT_ 65536
#define EPS_ 0.12f

typedef _Float16 f16;
typedef f16 f16x2 __attribute__((ext_vector_type(2)));
typedef f16 f16x4 __attribute__((ext_vector_type(4)));
typedef f16 f16x8 __attribute__((ext_vector_type(8)));
typedef float f32x4 __attribute__((ext_vector_type(4)));

// ---- ws layout (bytes) ----
#define OFF_XH   ((size_t)0)                 // f16 x, tiled [512 tblk][16 co][128 t][32 c]
#define OFF_CBH  ((size_t)67108864)          // f16 cb, tiled [8 kblk][16 co][128 k][32 c]
#define OFF_CBT  ((size_t)68157440)          // fp32 cbT4 [128 cq][1024 k] float4
#define OFF_KN   ((size_t)70254592)          // fp32 knorm [1024]
#define OFF_IDX  ((size_t)70258688)          // int idx [65536]
#define OFF_CNT  ((size_t)70520832)          // int count
#define OFF_LST  ((size_t)70521088)          // int worklist [65536]
#define WS_NEED  ((size_t)70783232)

#define GLOAD(g, l) __builtin_amdgcn_global_load_lds( \
    (__attribute__((address_space(1))) const unsigned int*)(const void*)(g), \
    (__attribute__((address_space(3))) unsigned int*)(void*)(l), 16, 0, 0)

// ---------------- Kernel 1: codebook norms + zero scalars + zero worklist count ----------------
__global__ void knorm_init_kernel(const float* __restrict__ cb,
                                  float* __restrict__ knorm,
                                  float* __restrict__ out,
                                  int* __restrict__ cnt) {
    const int k = blockIdx.x;
    const int lane = threadIdx.x;
    const float* row = cb + (size_t)k * C_;
    float s = 0.f;
#pragma unroll
    for (int j = 0; j < C_ / 64; ++j) {
        float v = row[lane + 64 * j];
        s += v * v;
    }
#pragma unroll
    for (int off = 32; off > 0; off >>= 1) s += __shfl_down(s, off, 64);
    if (lane == 0) knorm[k] = s;
    if (k == 0 && lane == 0) {
        out[(size_t)N_ * C_ * T_ + 0] = 0.f;
        out[(size_t)N_ * C_ * T_ + 1] = 0.f;
        *cnt = 0;
    }
}

// ---------------- Kernel 2: codebook -> f16 tiled AND fp32 transposed ----------------
__global__ void __launch_bounds__(256) conv_cb2_kernel(const float* __restrict__ cb,
                                                       f16* __restrict__ cbws,
                                                       float4* __restrict__ cbT4) {
    const int tid = threadIdx.x;
    const int b = blockIdx.x;                 // 128 blocks
    {   // f16 tiled chunk: kblk=b>>4, co=b&15
        const int kblk = b >> 4, co = b & 15;
        const float* src = cb + (size_t)kblk * 128 * C_ + co * 32;
        f16* dst = cbws + (size_t)kblk * 65536 + (size_t)co * 4096;
#pragma unroll
        for (int j = 0; j < 4; ++j) {
            int f = tid + 256 * j;
            int k_l = f >> 3;
            int c4 = (f & 7) * 4;
            float4 v = *(const float4*)(src + (size_t)k_l * C_ + c4);
            f16x4 h = {(f16)v.x, (f16)v.y, (f16)v.z, (f16)v.w};
            *(f16x4*)(dst + (size_t)k_l * 32 + c4) = h;
        }
    }
    {   // cbT4: cq = b; coalesced writes over k
        const int cq = b;
#pragma unroll
        for (int j = 0; j < 4; ++j) {
            int k = tid + 256 * j;
            float4 v = *(const float4*)(cb + (size_t)k * C_ + cq * 4);
            cbT4[(size_t)cq * 1024 + k] = v;
        }
    }
}

// ---------------- Kernel 3: convert x to tiled f16 (transpose c<->t) ----------------
__global__ void __launch_bounds__(256) conv_x_kernel(const float* __restrict__ x,
                                                     f16* __restrict__ xws) {
    __shared__ f16 trans[128 * 34];
    const int tid = threadIdx.x;
    const int b = blockIdx.x;                 // 512 t-tiles
    const int n = b >> 4;
    const int t0 = (b & 15) << 7;
    const float* xb = x + (size_t)n * C_ * T_ + t0;
    f16* outb = xws + (size_t)b * 65536;
    const int cp = tid >> 5;
    const int s = tid & 31;
    for (int co = 0; co < 16; ++co) {
        __syncthreads();
#pragma unroll
        for (int j = 0; j < 2; ++j) {
            int cpp = cp + 8 * j;
            int c0 = cpp * 2;
            float4 v0 = *(const float4*)(xb + (size_t)(co * 32 + c0) * T_ + s * 4);
            float4 v1 = *(const float4*)(xb + (size_t)(co * 32 + c0 + 1) * T_ + s * 4);
            f16x2 w0 = {(f16)v0.x, (f16)v1.x};
            f16x2 w1 = {(f16)v0.y, (f16)v1.y};
            f16x2 w2 = {(f16)v0.z, (f16)v1.z};
            f16x2 w3 = {(f16)v0.w, (f16)v1.w};
            *(f16x2*)&trans[(s * 4 + 0) * 34 + c0] = w0;
            *(f16x2*)&trans[(s * 4 + 1) * 34 + c0] = w1;
            *(f16x2*)&trans[(s * 4 + 2) * 34 + c0] = w2;
            *(f16x2*)&trans[(s * 4 + 3) * 34 + c0] = w3;
        }
        __syncthreads();
#pragma unroll
        for (int j = 0; j < 8; ++j) {
            int p = tid + 256 * j;
            int t_l = p >> 4;
            int cpo = p & 15;
            f16x2 v = *(const f16x2*)&trans[t_l * 34 + cpo * 2];
            *(f16x2*)(outb + (size_t)co * 4096 + t_l * 32 + cpo * 2) = v;
        }
    }
}

// ---------------- Kernel 4: fused MFMA distance over all K + top2 + worklist ----------------
// grid 512 (one block per t-tile of 128). Per-lane running top2 across 8 kblks.
__global__ void __launch_bounds__(256) mfma_fused_kernel(const f16* __restrict__ xws,
                                                         const f16* __restrict__ cbws,
                                                         const float* __restrict__ knorm,
                                                         int* __restrict__ idx,
                                                         int* __restrict__ cnt,
                                                         int* __restrict__ list) {
    __shared__ __align__(16) char Ab[2][8192];
    __shared__ __align__(16) char Bb[2][8192];
    __shared__ float mrg[128 * 2 * 3];

    const int tid = threadIdx.x;
    const int lane = tid & 63, w = tid >> 6;
    const int wy = w >> 1, wx = w & 1;
    const int col = lane & 15, quad = lane >> 4;
    const int tblk = blockIdx.x;

    const char* gA = (const char*)xws + (size_t)tblk * 131072 + w * 2048 + lane * 16;
    const char* gB = (const char*)cbws + w * 2048 + lane * 16;

    float rv1[4][4], rv2[4][4];
    int ri1[4][4];
#pragma unroll
    for (int ti = 0; ti < 4; ++ti)
#pragma unroll
        for (int reg = 0; reg < 4; ++reg) { rv1[ti][reg] = 3.4e38f; rv2[ti][reg] = 3.4e38f; ri1[ti][reg] = 0; }

    int cur = 0;
    // prologue: stage (kblk=0, co=0) into buf 0
    GLOAD(gA, Ab[0] + w * 2048);
    GLOAD(gA + 1024, Ab[0] + w * 2048 + 1024);
    GLOAD(gB, Bb[0] + w * 2048);
    GLOAD(gB + 1024, Bb[0] + w * 2048 + 1024);

    for (int kblk = 0; kblk < 8; ++kblk) {
        float kn[4];
#pragma unroll
        for (int ki = 0; ki < 4; ++ki) kn[ki] = knorm[kblk * 128 + wx * 64 + ki * 16 + col];

        f32x4 acc[4][4];
#pragma unroll
        for (int i = 0; i < 4; ++i)
#pragma unroll
            for (int j = 0; j < 4; ++j) acc[i][j] = (f32x4){0.f, 0.f, 0.f, 0.f};

        for (int co = 0; co < 16; ++co) {
            __syncthreads();
            // prefetch next chunk into the other buffer
            int nk = kblk, nc = co + 1;
            if (nc == 16) { nc = 0; ++nk; }
            if (nk < 8) {
                const char* nA = gA + (size_t)nc * 8192;
                const char* nB = gB + (size_t)nk * 131072 + (size_t)nc * 8192;
                char* dA = Ab[cur ^ 1] + w * 2048;
                char* dB = Bb[cur ^ 1] + w * 2048;
                GLOAD(nA, dA);
                GLOAD(nA + 1024, dA + 1024);
                GLOAD(nB, dB);
                GLOAD(nB + 1024, dB + 1024);
            }
            const f16* As = (const f16*)Ab[cur];
            const f16* Bs = (const f16*)Bb[cur];
            f16x8 af[4], bf[4];
#pragma unroll
            for (int ti = 0; ti < 4; ++ti) af[ti] = *(const f16x8*)(As + (wy * 64 + ti * 16 + col) * 32 + quad * 8);
#pragma unroll
            for (int ki = 0; ki < 4; ++ki) bf[ki] = *(const f16x8*)(Bs + (wx * 64 + ki * 16 + col) * 32 + quad * 8);
#pragma unroll
            for (int ti = 0; ti < 4; ++ti)
#pragma unroll
                for (int ki = 0; ki < 4; ++ki)
                    acc[ti][ki] = __builtin_amdgcn_mfma_f32_16x16x32_f16(af[ti], bf[ki], acc[ti][ki], 0, 0, 0);
            cur ^= 1;
        }
        // fold this kblk's scores into per-lane running top2 (k ascending within a lane)
#pragma unroll
        for (int ti = 0; ti < 4; ++ti)
#pragma unroll
            for (int reg = 0; reg < 4; ++reg) {
#pragma unroll
                for (int ki = 0; ki < 4; ++ki) {
                    float sc = fmaf(-2.f, acc[ti][ki][reg], kn[ki]);
                    int kg = kblk * 128 + wx * 64 + ki * 16 + col;
                    if (sc < rv1[ti][reg]) { rv2[ti][reg] = rv1[ti][reg]; rv1[ti][reg] = sc; ri1[ti][reg] = kg; }
                    else if (sc < rv2[ti][reg]) rv2[ti][reg] = sc;
                }
            }
    }

    // final reduce: 16 col-lanes hold disjoint k-slices of each row
#pragma unroll
    for (int ti = 0; ti < 4; ++ti)
#pragma unroll
        for (int reg = 0; reg < 4; ++reg) {
            float v1 = rv1[ti][reg], v2 = rv2[ti][reg];
            int i1 = ri1[ti][reg];
#pragma unroll
            for (int m = 1; m <= 8; m <<= 1) {
                float ov1 = __shfl_xor(v1, m, 64);
                float ov2 = __shfl_xor(v2, m, 64);
                int oi1 = __shfl_xor(i1, m, 64);
                float nv2 = fminf(fminf(v2, ov2), fmaxf(v1, ov1));
                if (ov1 < v1 || (ov1 == v1 && oi1 < i1)) { v1 = ov1; i1 = oi1; }
                v2 = nv2;
            }
            if (col == 0) {
                int t_l = wy * 64 + ti * 16 + quad * 4 + reg;
                float* p = &mrg[(t_l * 2 + wx) * 3];
                p[0] = v1; p[1] = __int_as_float(i1); p[2] = v2;
            }
        }
    __syncthreads();
    if (tid < 128) {
        const float* pa = &mrg[tid * 6];
        const float* pb = &mrg[tid * 6 + 3];
        float v1 = pa[0], v2 = pa[2];
        int i1 = __float_as_int(pa[1]);
        float ov1 = pb[0], ov2 = pb[2];
        int oi1 = __float_as_int(pb[1]);
        float nv2 = fminf(fminf(v2, ov2), fmaxf(v1, ov1));
        if (ov1 < v1 || (ov1 == v1 && oi1 < i1)) { v1 = ov1; i1 = oi1; }
        const int r = tblk * 128 + tid;
        idx[r] = i1;
        if (nv2 <= v1 + 2.f * EPS_) {
            int p = atomicAdd(cnt, 1);
            list[p] = r;
        }
    }
}

// ---------------- Kernel 5: exact fp32 rescan, coalesced via cbT4 ----------------
__global__ void __launch_bounds__(256) rescan3_kernel(const float* __restrict__ x,
                                                      const float4* __restrict__ cbT4,
                                                      const float* __restrict__ knorm,
                                                      const int* __restrict__ cnt,
                                                      const int* __restrict__ list,
                                                      int* __restrict__ idx) {
    __shared__ float xrow[2][512];
    __shared__ float redv[2][256];
    __shared__ int redk[2][256];
    const int tid = threadIdx.x;
    const int nf = *cnt;
    for (int base = blockIdx.x * 2; base < nf; base += gridDim.x * 2) {
        const int nr = (nf - base < 2) ? (nf - base) : 2;
        __syncthreads();
        for (int i = tid; i < nr * 512; i += 256) {
            int r = i >> 9, c = i & 511;
            int rr = list[base + r];
            xrow[r][c] = x[(size_t)(rr >> 11) * C_ * T_ + (size_t)c * T_ + (rr & 2047)];
        }
        __syncthreads();
        float acc[4][2];
#pragma unroll
        for (int j = 0; j < 4; ++j) { acc[j][0] = 0.f; acc[j][1] = 0.f; }
#pragma unroll 4
        for (int cq = 0; cq < 128; ++cq) {
            float4 xv0 = *(const float4*)&xrow[0][cq * 4];
            float4 xv1 = *(const float4*)&xrow[1][cq * 4];
#pragma unroll
            for (int j = 0; j < 4; ++j) {
                float4 cv = cbT4[(size_t)cq * 1024 + tid + 256 * j];
                acc[j][0] = fmaf(cv.x, xv0.x, acc[j][0]);
                acc[j][0] = fmaf(cv.y, xv0.y, acc[j][0]);
                acc[j][0] = fmaf(cv.z, xv0.z, acc[j][0]);
                acc[j][0] = fmaf(cv.w, xv0.w, acc[j][0]);
                acc[j][1] = fmaf(cv.x, xv1.x, acc[j][1]);
                acc[j][1] = fmaf(cv.y, xv1.y, acc[j][1]);
                acc[j][1] = fmaf(cv.z, xv1.z, acc[j][1]);
                acc[j][1] = fmaf(cv.w, xv1.w, acc[j][1]);
            }
        }
#pragma unroll
        for (int r = 0; r < 2; ++r) {
            float bv = 3.4e38f;
            int bk = 0;
#pragma unroll
            for (int j = 0; j < 4; ++j) {
                int k = tid + 256 * j;
                float sc = fmaf(-2.f, acc[j][r], knorm[k]);
                if (sc < bv) { bv = sc; bk = k; }
            }
            redv[r][tid] = bv;
            redk[r][tid] = bk;
        }
        __syncthreads();
        for (int off = 128; off > 0; off >>= 1) {
            if (tid < off) {
#pragma unroll
                for (int r = 0; r < 2; ++r) {
                    float ov = redv[r][tid + off];
                    int ok = redk[r][tid + off];
                    if (ov < redv[r][tid] || (ov == redv[r][tid] && ok < redk[r][tid])) {
                        redv[r][tid] = ov;
                        redk[r][tid] = ok;
                    }
                }
            }
            __syncthreads();
        }
        if (tid == 0) {
            for (int r = 0; r < nr; ++r) idx[list[base + r]] = redk[r][0];
        }
    }
}

// ---------------- Kernel 6: gather codebook rows to output ----------------
__global__ void __launch_bounds__(256) gather_kernel(const float* __restrict__ cb,
                                                     const int* __restrict__ idx,
                                                     float* __restrict__ out) {
    __shared__ int idxs[128];
    const int tid = threadIdx.x;
    const int b = blockIdx.x;
    const int n = b >> 4;
    const int t0 = (b & 15) << 7;
    if (tid < 128) idxs[tid] = idx[b * 128 + tid];
    __syncthreads();
    const int tg = (tid & 31) * 4;
    const int cs = tid >> 5;
    const float* r0 = cb + (size_t)idxs[tg + 0] * C_;
    const float* r1 = cb + (size_t)idxs[tg + 1] * C_;
    const float* r2 = cb + (size_t)idxs[tg + 2] * C_;
    const float* r3 = cb + (size_t)idxs[tg + 3] * C_;
    float* obase = out + (size_t)n * C_ * T_ + t0 + tg;
    for (int c = cs; c < C_; c += 8) {
        float4 v;
        v.x = r0[c]; v.y = r1[c]; v.z = r2[c]; v.w = r3[c];
        *(float4*)&obase[(size_t)c * T_] = v;
    }
}

// ---------------- Fallback (round-1 fp32 path, verified correct) ----------------
__global__ void __launch_bounds__(256)
vq_fallback_kernel(const float* __restrict__ x, const float* __restrict__ cb,
                   const float* __restrict__ knorm, float* __restrict__ out) {
    __shared__ float smem[4416];
    float* Xs = smem;
    float* Bs = smem + 2048;
    float* kns = smem + 4160;
    int* idxs = (int*)(smem + 4288);
    float* redv = smem;
    int* redk = (int*)(smem + 2048);

    const int tid = threadIdx.x;
    const int tx = tid & 15;
    const int ty = tid >> 4;
    const int b = blockIdx.x;
    const int n = b >> 4;
    const int t0 = (b & 15) * 128;
    const float* xbase = x + (size_t)n * C_ * T_ + t0;

    float best[8];
    int bestk[8];
#pragma unroll
    for (int i = 0; i < 8; ++i) { best[i] = 3.4e38f; bestk[i] = 0; }

    for (int k0 = 0; k0 < K_; k0 += 128) {
        if (tid < 128) kns[tid] = knorm[k0 + tid];
        float acc[8][8];
#pragma unroll
        for (int i = 0; i < 8; ++i)
#pragma unroll
            for (int j = 0; j < 8; ++j) acc[i][j] = 0.f;
        for (int cc = 0; cc < C_; cc += 16) {
            __syncthreads();
#pragma unroll
            for (int j = 0; j < 2; ++j) {
                int f = tid + 256 * j;
                int cl = f >> 5;
                int t4 = (f & 31) * 4;
                float4 v = *(const float4*)(xbase + (size_t)(cc + cl) * T_ + t4);
                *(float4*)&Xs[cl * 128 + t4] = v;
            }
#pragma unroll
            for (int j = 0; j < 2; ++j) {
                int f = tid + 256 * j;
                int kl = f >> 2;
                int c4 = (f & 3) * 4;
                float4 v = *(const float4*)(cb + (size_t)(k0 + kl) * C_ + cc + c4);
                Bs[(c4 + 0) * 132 + kl] = v.x;
                Bs[(c4 + 1) * 132 + kl] = v.y;
                Bs[(c4 + 2) * 132 + kl] = v.z;
                Bs[(c4 + 3) * 132 + kl] = v.w;
            }
            __syncthreads();
#pragma unroll
            for (int c = 0; c < 16; ++c) {
                float4 xa = *(const float4*)&Xs[c * 128 + ty * 8];
                float4 xb2 = *(const float4*)&Xs[c * 128 + ty * 8 + 4];
                float4 ba = *(const float4*)&Bs[c * 132 + tx * 8];
                float4 bb = *(const float4*)&Bs[c * 132 + tx * 8 + 4];
                float xr[8] = {xa.x, xa.y, xa.z, xa.w, xb2.x, xb2.y, xb2.z, xb2.w};
                float br[8] = {ba.x, ba.y, ba.z, ba.w, bb.x, bb.y, bb.z, bb.w};
#pragma unroll
                for (int i = 0; i < 8; ++i)
#pragma unroll
                    for (int j = 0; j < 8; ++j)
                        acc[i][j] = fmaf(xr[i], br[j], acc[i][j]);
            }
        }
#pragma unroll
        for (int j = 0; j < 8; ++j) {
            const int kk = k0 + tx * 8 + j;
            const float kn = kns[tx * 8 + j];
#pragma unroll
            for (int i = 0; i < 8; ++i) {
                float s = fmaf(-2.f, acc[i][j], kn);
                if (s < best[i]) { best[i] = s; bestk[i] = kk; }
            }
        }
        __syncthreads();
    }
#pragma unroll
    for (int i = 0; i < 8; ++i) {
        redv[(ty * 8 + i) * 16 + tx] = best[i];
        redk[(ty * 8 + i) * 16 + tx] = bestk[i];
    }
    __syncthreads();
    if (tid < 128) {
        float bv = redv[tid * 16];
        int bk = redk[tid * 16];
#pragma unroll
        for (int j = 1; j < 16; ++j) {
            float v = redv[tid * 16 + j];
            int kj = redk[tid * 16 + j];
            if (v < bv || (v == bv && kj < bk)) { bv = v; bk = kj; }
        }
        idxs[tid] = bk;
    }
    __syncthreads();
    const int tg = (tid & 31) * 4;
    const int cs = tid >> 5;
    const float* r0 = cb + (size_t)idxs[tg + 0] * C_;
    const float* r1 = cb + (size_t)idxs[tg + 1] * C_;
    const float* r2 = cb + (size_t)idxs[tg + 2] * C_;
    const float* r3 = cb + (size_t)idxs[tg + 3] * C_;
    float* obase = out + (size_t)n * C_ * T_ + t0 + tg;
    for (int c = cs; c < C_; c += 8) {
        float4 v;
        v.x = r0[c]; v.y = r1[c]; v.z = r2[c]; v.w = r3[c];
        *(float4*)&obase[(size_t)c * T_] = v;
    }
}

extern "C" void kernel_launch(void* const* d_in, const int* in_sizes, int n_in,
                              void* d_out, int out_size, void* d_ws, size_t ws_size,
                              hipStream_t stream) {
    const float* x = (const float*)d_in[0];    // [32,512,2048] fp32
    const float* cb = (const float*)d_in[1];   // [1024,512] fp32
    float* out = (float*)d_out;
    char* ws = (char*)d_ws;

    if (ws_size < WS_NEED) {
        float* kn = (float*)ws;
        int* cnt0 = (int*)(ws + 4096);
        knorm_init_kernel<<<K_, 64, 0, stream>>>(cb, kn, out, cnt0);
        vq_fallback_kernel<<<(NT_) / 128, 256, 0, stream>>>(x, cb, kn, out);
        return;
    }

    f16* xws = (f16*)(ws + OFF_XH);
    f16* cbws = (f16*)(ws + OFF_CBH);
    float4* cbT4 = (float4*)(ws + OFF_CBT);
    float* knorm = (float*)(ws + OFF_KN);
    int* idx = (int*)(ws + OFF_IDX);
    int* cnt = (int*)(ws + OFF_CNT);
    int* list = (int*)(ws + OFF_LST);

    knorm_init_kernel<<<K_, 64, 0, stream>>>(cb, knorm, out, cnt);
    conv_cb2_kernel<<<128, 256, 0, stream>>>(cb, cbws, cbT4);
    conv_x_kernel<<<512, 256, 0, stream>>>(x, xws);
    mfma_fused_kernel<<<512, 256, 0, stream>>>(xws, cbws, knorm, idx, cnt, list);
    rescan3_kernel<<<256, 256, 0, stream>>>(x, cbT4, knorm, cnt, list, idx);
    gather_kernel<<<512, 256, 0, stream>>>(cb, idx, out);
}